// Round 9
// baseline (174.282 us; speedup 1.0000x reference)
//
#include <hip/hip_runtime.h>
#include <hip/hip_fp16.h>

#define TPB 256
#define LOG_NPB 9
#define NPB 512            // nodes per bucket (bucket = dst >> 9)
#define HPB 256            // packed words per bucket (node pairs)
#define SPLIT 16           // blocks per bucket in accumulation passes
#define CHUNK 4096         // edges per bucketing block
#define RCAP 40            // per-(chunk,bucket) LDS region cap (λ=21; overflow handled)

// GCN collapse (in-dim=1, out-dim=2):
//   deg[n] = 1 + #incoming; dinv = deg^-1/2; xd = x*dinv
//   t1[n] = sum_{e:dst=n} xd[src];  s = dinv*(t1+xd)
//   g[n][k] = sum_j relu(s*W1[j]+b1[j])*W2[j][k];  gd = g*dinv (packed f16x2)
//   t2[n][k] = sum_{e:dst=n} gd[src][k]
//   o = dinv*(t2+gd) + b2;  out = log_softmax(o)
// Cost currency (R6 ablation): LDS-atomic instructions per edge (~28-35us per
// atomic-pass). ALL three aggregation passes now use ONE ds_pk_add_f16/edge:
//   deg: +1.0h into node-pair half (exact, f16 ints <= 2048)
//   pass1: +f16(xd[src]) into node-pair half (f32 combine across slices)
//   pass2: +(g0,g1) packed per node

__device__ __forceinline__ void lds_pk_add_f16(unsigned* addr, unsigned val) {
  asm volatile("ds_pk_add_f16 %0, %1"
               :: "v"((unsigned)(unsigned long long)addr), "v"(val)
               : "memory");
}

__global__ void k_reset(int* __restrict__ gcur, int K) {
  int i = blockIdx.x * blockDim.x + threadIdx.x;
  if (i < K) gcur[i] = 0;
}

// Single-atomic region-scatter bucketing (8-edge ILP batches).
__global__ __launch_bounds__(TPB) void
k_bucket(const int* __restrict__ src, const int* __restrict__ dst,
         int E, int K, int capG,
         int* __restrict__ gcur, unsigned int* __restrict__ packed) {
  extern __shared__ unsigned smem[];
  unsigned* stage = smem;                              // K*RCAP
  int* cur = (int*)(smem + (size_t)K * RCAP);          // K
  int* res = cur + K;                                  // K

  const int t = threadIdx.x;
  const int e0 = blockIdx.x * CHUNK;
  const int e1 = min(e0 + CHUNK, E);

  for (int b = t; b < K; b += TPB) cur[b] = 0;
  __syncthreads();

  for (int base = e0 + 8 * t; base < e1; base += 8 * TPB) {
    if (base + 8 <= e1) {
      int4 dv0 = *reinterpret_cast<const int4*>(dst + base);
      int4 dv1 = *reinterpret_cast<const int4*>(dst + base + 4);
      int4 sv0 = *reinterpret_cast<const int4*>(src + base);
      int4 sv1 = *reinterpret_cast<const int4*>(src + base + 4);
      int d[8] = {dv0.x, dv0.y, dv0.z, dv0.w, dv1.x, dv1.y, dv1.z, dv1.w};
      int s[8] = {sv0.x, sv0.y, sv0.z, sv0.w, sv1.x, sv1.y, sv1.z, sv1.w};
#pragma unroll
      for (int j = 0; j < 8; ++j) {
        int b = d[j] >> LOG_NPB;
        unsigned pk = ((unsigned)s[j] << LOG_NPB) | (unsigned)(d[j] & (NPB - 1));
        int p = atomicAdd(&cur[b], 1);
        if (p < RCAP) {
          stage[b * RCAP + p] = pk;
        } else {                       // rare overflow: direct global slot
          int gp = atomicAdd(&gcur[b], 1);
          if (gp < capG) packed[(size_t)b * capG + gp] = pk;
        }
      }
    } else {
      for (int idx = base; idx < e1; ++idx) {
        int d = dst[idx], s = src[idx];
        int b = d >> LOG_NPB;
        unsigned pk = ((unsigned)s << LOG_NPB) | (unsigned)(d & (NPB - 1));
        int p = atomicAdd(&cur[b], 1);
        if (p < RCAP) {
          stage[b * RCAP + p] = pk;
        } else {
          int gp = atomicAdd(&gcur[b], 1);
          if (gp < capG) packed[(size_t)b * capG + gp] = pk;
        }
      }
    }
  }
  __syncthreads();

  if (t < K) {
    int c = min(cur[t], RCAP);
    res[t] = (c > 0) ? atomicAdd(&gcur[t], c) : 0;
  }
  __syncthreads();

  const int tot = K * RCAP;
  for (int i = t; i < tot; i += TPB) {
    int b = i / RCAP;
    int pos = i - b * RCAP;
    if (pos < min(cur[b], RCAP)) {
      int gp = res[b] + pos;
      if (gp < capG) packed[(size_t)b * capG + gp] = stage[i];
    }
  }
}

__device__ __forceinline__ void slice_range(int cnt, int s, int& off0, int& off1) {
  off0 = (int)(((long long)cnt * s) / SPLIT) & ~3;
  off1 = (s == SPLIT - 1) ? cnt : (int)(((long long)cnt * (s + 1)) / SPLIT) & ~3;
}

// deg: one pk atomic per edge; +1.0h into the node's half of its pair word
__global__ __launch_bounds__(TPB) void
k_deg(const unsigned int* __restrict__ packed, const int* __restrict__ gcur,
      int cap, unsigned* __restrict__ pdeg_pk, int halfNpad) {
  int b = blockIdx.x / SPLIT, s = blockIdx.x % SPLIT;
  __shared__ unsigned binsp[HPB];
  for (int i = threadIdx.x; i < HPB; i += TPB) binsp[i] = 0u;
  __syncthreads();
  int cnt = min(gcur[b], cap);
  int off0, off1; slice_range(cnt, s, off0, off1);
  const unsigned int* base = packed + (size_t)b * cap;
  int len = off1 - off0;
  int nfull = len >> 3;
#define DEG1(P) { unsigned l_ = (P) & (NPB - 1); \
  lds_pk_add_f16(&binsp[l_ >> 1], (l_ & 1) ? 0x3C000000u : 0x00003C00u); }
  for (int g = threadIdx.x; g < nfull; g += TPB) {
    int e = off0 + (g << 3);
    uint4 pa = *reinterpret_cast<const uint4*>(base + e);
    uint4 pb = *reinterpret_cast<const uint4*>(base + e + 4);
    DEG1(pa.x) DEG1(pa.y) DEG1(pa.z) DEG1(pa.w)
    DEG1(pb.x) DEG1(pb.y) DEG1(pb.z) DEG1(pb.w)
  }
  for (int e = off0 + (nfull << 3) + threadIdx.x; e < off1; e += TPB)
    DEG1(base[e])
#undef DEG1
  __syncthreads();
  int nb = b << (LOG_NPB - 1);
  for (int i = threadIdx.x; i < HPB; i += TPB)
    pdeg_pk[s * halfNpad + nb + i] = binsp[i];
}

// node-pair version: word index == pair index
__global__ void k_dinv(const unsigned* __restrict__ pdeg_pk, const float* __restrict__ x,
                       float* __restrict__ dinv, float* __restrict__ xd,
                       int N, int halfNpad) {
  int i2 = blockIdx.x * TPB + threadIdx.x;
  int n0 = 2 * i2;
  if (n0 >= N) return;
  float d0 = 1.f, d1 = 1.f;  // self-loops
#pragma unroll
  for (int s = 0; s < SPLIT; ++s) {
    unsigned v = pdeg_pk[s * halfNpad + i2];
    __half2 h = *reinterpret_cast<__half2*>(&v);
    d0 += __low2float(h);
    d1 += __high2float(h);
  }
  float di0 = rsqrtf(d0);
  dinv[n0] = di0;
  xd[n0] = x[n0] * di0;
  if (n0 + 1 < N) {
    float di1 = rsqrtf(d1);
    dinv[n0 + 1] = di1;
    xd[n0 + 1] = x[n0 + 1] * di1;
  }
}

// pass1: one pk atomic per edge; f16(xd[src]) into node half
__global__ __launch_bounds__(TPB) void
k_pass1(const unsigned int* __restrict__ packed, const int* __restrict__ gcur,
        int cap, const float* __restrict__ xd, unsigned* __restrict__ pt1_pk,
        int halfNpad) {
  int b = blockIdx.x / SPLIT, s = blockIdx.x % SPLIT;
  __shared__ unsigned binsp[HPB];
  for (int i = threadIdx.x; i < HPB; i += TPB) binsp[i] = 0u;
  __syncthreads();
  int cnt = min(gcur[b], cap);
  int off0, off1; slice_range(cnt, s, off0, off1);
  const unsigned int* base = packed + (size_t)b * cap;
  int len = off1 - off0;
  int nfull = len >> 3;
  for (int g = threadIdx.x; g < nfull; g += TPB) {
    int e = off0 + (g << 3);
    uint4 pa = *reinterpret_cast<const uint4*>(base + e);
    uint4 pb = *reinterpret_cast<const uint4*>(base + e + 4);
    float v0 = xd[pa.x >> LOG_NPB];
    float v1 = xd[pa.y >> LOG_NPB];
    float v2 = xd[pa.z >> LOG_NPB];
    float v3 = xd[pa.w >> LOG_NPB];
    float v4 = xd[pb.x >> LOG_NPB];
    float v5 = xd[pb.y >> LOG_NPB];
    float v6 = xd[pb.z >> LOG_NPB];
    float v7 = xd[pb.w >> LOG_NPB];
#define P1(P, V) { unsigned l_ = (P) & (NPB - 1); \
  unsigned hv_ = (unsigned)__half_as_ushort(__float2half(V)); \
  lds_pk_add_f16(&binsp[l_ >> 1], hv_ << ((l_ & 1) * 16)); }
    P1(pa.x, v0) P1(pa.y, v1) P1(pa.z, v2) P1(pa.w, v3)
    P1(pb.x, v4) P1(pb.y, v5) P1(pb.z, v6) P1(pb.w, v7)
  }
  for (int e = off0 + (nfull << 3) + threadIdx.x; e < off1; e += TPB) {
    unsigned p = base[e];
    P1(p, xd[p >> LOG_NPB])
  }
#undef P1
  __syncthreads();
  int nb = b << (LOG_NPB - 1);
  for (int i = threadIdx.x; i < HPB; i += TPB)
    pt1_pk[s * halfNpad + nb + i] = binsp[i];
}

__global__ void k_node(const unsigned* __restrict__ pt1_pk, const float* __restrict__ xd,
                       const float* __restrict__ dinv,
                       const float* __restrict__ W1, const float* __restrict__ b1,
                       const float* __restrict__ W2,
                       unsigned* __restrict__ gdp, int N, int halfNpad) {
  int i2 = blockIdx.x * TPB + threadIdx.x;
  int n0 = 2 * i2;
  if (n0 >= N) return;
  float t0 = 0.f, t1 = 0.f;
#pragma unroll
  for (int s = 0; s < SPLIT; ++s) {
    unsigned v = pt1_pk[s * halfNpad + i2];
    __half2 h = *reinterpret_cast<__half2*>(&v);
    t0 += __low2float(h);
    t1 += __high2float(h);
  }
  {
    float di = dinv[n0];
    float sv = di * (t0 + xd[n0]);
    float g0 = 0.f, g1 = 0.f;
#pragma unroll
    for (int j = 0; j < 16; ++j) {
      float h = fmaxf(fmaf(sv, W1[j], b1[j]), 0.f);
      g0 = fmaf(h, W2[2 * j], g0);
      g1 = fmaf(h, W2[2 * j + 1], g1);
    }
    __half2 h2 = __floats2half2_rn(g0 * di, g1 * di);
    gdp[n0] = *reinterpret_cast<unsigned*>(&h2);
  }
  if (n0 + 1 < N) {
    float di = dinv[n0 + 1];
    float sv = di * (t1 + xd[n0 + 1]);
    float g0 = 0.f, g1 = 0.f;
#pragma unroll
    for (int j = 0; j < 16; ++j) {
      float h = fmaxf(fmaf(sv, W1[j], b1[j]), 0.f);
      g0 = fmaf(h, W2[2 * j], g0);
      g1 = fmaf(h, W2[2 * j + 1], g1);
    }
    __half2 h2 = __floats2half2_rn(g0 * di, g1 * di);
    gdp[n0 + 1] = *reinterpret_cast<unsigned*>(&h2);
  }
}

// pass2: one pk atomic per edge, (g0,g1) per node; raw u32 partial writeout
__global__ __launch_bounds__(TPB) void
k_pass2(const unsigned int* __restrict__ packed, const int* __restrict__ gcur,
        int cap, const unsigned* __restrict__ gdp, unsigned* __restrict__ pt2_pk,
        int Npad) {
  int b = blockIdx.x / SPLIT, s = blockIdx.x % SPLIT;
  __shared__ unsigned bins[NPB];
  for (int i = threadIdx.x; i < NPB; i += TPB) bins[i] = 0u;
  __syncthreads();
  int cnt = min(gcur[b], cap);
  int off0, off1; slice_range(cnt, s, off0, off1);
  const unsigned int* base = packed + (size_t)b * cap;
  int len = off1 - off0;
  int nfull = len >> 3;
  for (int g = threadIdx.x; g < nfull; g += TPB) {
    int e = off0 + (g << 3);
    uint4 pa = *reinterpret_cast<const uint4*>(base + e);
    uint4 pb = *reinterpret_cast<const uint4*>(base + e + 4);
    unsigned v0 = gdp[pa.x >> LOG_NPB];
    unsigned v1 = gdp[pa.y >> LOG_NPB];
    unsigned v2 = gdp[pa.z >> LOG_NPB];
    unsigned v3 = gdp[pa.w >> LOG_NPB];
    unsigned v4 = gdp[pb.x >> LOG_NPB];
    unsigned v5 = gdp[pb.y >> LOG_NPB];
    unsigned v6 = gdp[pb.z >> LOG_NPB];
    unsigned v7 = gdp[pb.w >> LOG_NPB];
    lds_pk_add_f16(&bins[pa.x & (NPB - 1)], v0);
    lds_pk_add_f16(&bins[pa.y & (NPB - 1)], v1);
    lds_pk_add_f16(&bins[pa.z & (NPB - 1)], v2);
    lds_pk_add_f16(&bins[pa.w & (NPB - 1)], v3);
    lds_pk_add_f16(&bins[pb.x & (NPB - 1)], v4);
    lds_pk_add_f16(&bins[pb.y & (NPB - 1)], v5);
    lds_pk_add_f16(&bins[pb.z & (NPB - 1)], v6);
    lds_pk_add_f16(&bins[pb.w & (NPB - 1)], v7);
  }
  for (int e = off0 + (nfull << 3) + threadIdx.x; e < off1; e += TPB) {
    unsigned int p = base[e];
    lds_pk_add_f16(&bins[p & (NPB - 1)], gdp[p >> LOG_NPB]);
  }
  __syncthreads();
  int nb = b << LOG_NPB;
  for (int i = threadIdx.x; i < NPB; i += TPB)
    pt2_pk[(size_t)s * Npad + nb + i] = bins[i];
}

__global__ void k_final(const unsigned* __restrict__ pt2_pk, const unsigned* __restrict__ gdp,
                        const float* __restrict__ dinv, const float* __restrict__ b2,
                        float* __restrict__ out, int N, int Npad) {
  int i = blockIdx.x * TPB + threadIdx.x;
  if (i >= N) return;
  float t0 = 0.f, t1 = 0.f;
#pragma unroll
  for (int s = 0; s < SPLIT; ++s) {
    unsigned v = pt2_pk[(size_t)s * Npad + i];
    __half2 h = *reinterpret_cast<__half2*>(&v);
    t0 += __low2float(h);
    t1 += __high2float(h);
  }
  unsigned gp = gdp[i];
  __half2 h = *reinterpret_cast<__half2*>(&gp);
  float di = dinv[i];
  float o0 = di * (t0 + __low2float(h)) + b2[0];
  float o1 = di * (t1 + __high2float(h)) + b2[1];
  float m = fmaxf(o0, o1);
  float l = m + logf(expf(o0 - m) + expf(o1 - m));
  out[2 * i] = o0 - l;
  out[2 * i + 1] = o1 - l;
}

extern "C" void kernel_launch(void* const* d_in, const int* in_sizes, int n_in,
                              void* d_out, int out_size, void* d_ws, size_t ws_size,
                              hipStream_t stream) {
  const float* x  = (const float*)d_in[0];
  const int*   ei = (const int*)d_in[1];
  const float* W1 = (const float*)d_in[2];
  const float* b1 = (const float*)d_in[3];
  const float* W2 = (const float*)d_in[4];
  const float* b2 = (const float*)d_in[5];

  const int N = in_sizes[0];      // x is [N,1]
  const int E = in_sizes[1] / 2;  // edge_index is [2,E]
  const int* src = ei;
  const int* dst = ei + E;

  const int K = (N + NPB - 1) >> LOG_NPB;   // 196
  const int Npad = K << LOG_NPB;            // 100352
  const int halfNpad = Npad >> 1;           // 50176
  int mean = (int)(((long long)E * NPB) / N);
  int cap = mean + mean / 16 + 512;
  cap = (cap + 3) & ~3;

  char* ws = (char*)d_ws;
  auto align256 = [&](size_t n) { char* p = ws; ws += (n + 255) & ~(size_t)255; return p; };

  int*          gcur   = (int*)align256((size_t)K * 4);
  unsigned int* packed = (unsigned int*)align256((size_t)K * cap * 4);
  float*        dinv   = (float*)align256((size_t)N * 4);
  float*        xd     = (float*)align256((size_t)N * 4);
  unsigned*     gdp    = (unsigned*)align256((size_t)N * 4);
  // shared region R: pdeg_pk / pt1_pk (SPLIT*halfNpad u32) and pt2_pk
  // (SPLIT*Npad u32) — sequentially dead -> alias
  unsigned*     R      = (unsigned*)align256((size_t)SPLIT * Npad * 4);
  unsigned*     pdeg_pk = R;
  unsigned*     pt1_pk  = R;
  unsigned*     pt2_pk  = R;

  float* out = (float*)d_out;

  int nb_pair   = ((N + 1) / 2 + TPB - 1) / TPB;
  int nb_node   = (N + TPB - 1) / TPB;
  int nb_bucket = (E + CHUNK - 1) / CHUNK;
  int nb_acc    = K * SPLIT;
  size_t sh_bucket = ((size_t)K * RCAP + 2 * (size_t)K) * 4;

  k_reset <<<(K + TPB - 1) / TPB, TPB, 0, stream>>>(gcur, K);
  k_bucket<<<nb_bucket, TPB, sh_bucket, stream>>>(src, dst, E, K, cap, gcur, packed);
  k_deg   <<<nb_acc, TPB, 0, stream>>>(packed, gcur, cap, pdeg_pk, halfNpad);
  k_dinv  <<<nb_pair, TPB, 0, stream>>>(pdeg_pk, x, dinv, xd, N, halfNpad);
  k_pass1 <<<nb_acc, TPB, 0, stream>>>(packed, gcur, cap, xd, pt1_pk, halfNpad);
  k_node  <<<nb_pair, TPB, 0, stream>>>(pt1_pk, xd, dinv, W1, b1, W2, gdp, N, halfNpad);
  k_pass2 <<<nb_acc, TPB, 0, stream>>>(packed, gcur, cap, gdp, pt2_pk, Npad);
  k_final <<<nb_node, TPB, 0, stream>>>(pt2_pk, gdp, dinv, b2, out, N, Npad);
}

// Round 10
// 173.785 us; speedup vs baseline: 1.0029x; 1.0029x over previous
//
#include <hip/hip_runtime.h>
#include <hip/hip_fp16.h>

#define TPB 256
#define LOG_NPB 9
#define NPB 512            // nodes per bucket (bucket = dst >> 9)
#define SPLIT 16           // blocks per bucket in accumulation passes
#define CHUNK 2048         // edges per bucketing block (= TPB*8, one ILP batch)
#define RCAP 26            // per-(chunk,bucket) LDS region cap (λ=10.5, +4.8σ; overflow handled)

// GCN collapse (in-dim=1, out-dim=2):
//   deg[n] = 1 + #incoming; dinv = deg^-1/2; xd = x*dinv
//   t1[n] = sum_{e:dst=n} xd[src];  s = dinv*(t1+xd)
//   g[n][k] = sum_j relu(s*W1[j]+b1[j])*W2[j][k];  gd = g*dinv (packed f16x2)
//   t2[n][k] = sum_{e:dst=n} gd[src][k]   (ONE ds_pk_add_f16 per edge)
//   o = dinv*(t2+gd) + b2;  out = log_softmax(o)
// Cost currency (R6 ablation): DS-pipe atomic instructions per edge at
// constant same-address collision rate (~28-35us per atomic-pass).
// R9 lesson: pk-packing two NODES per word doubles collisions -> regression;
// pk only for two VALUES of one node (pass2). This is R8 + bucket occupancy
// retune (CHUNK 2048 / RCAP 26: 21.9KB LDS -> 7 blocks/CU vs 4).

__device__ __forceinline__ void lds_pk_add_f16(unsigned* addr, unsigned val) {
  asm volatile("ds_pk_add_f16 %0, %1"
               :: "v"((unsigned)(unsigned long long)addr), "v"(val)
               : "memory");
}

__global__ void k_reset(int* __restrict__ gcur, int K) {
  int i = blockIdx.x * blockDim.x + threadIdx.x;
  if (i < K) gcur[i] = 0;
}

// Single-atomic region-scatter bucketing (8-edge ILP batch).
__global__ __launch_bounds__(TPB) void
k_bucket(const int* __restrict__ src, const int* __restrict__ dst,
         int E, int K, int capG,
         int* __restrict__ gcur, unsigned int* __restrict__ packed) {
  extern __shared__ unsigned smem[];
  unsigned* stage = smem;                              // K*RCAP
  int* cur = (int*)(smem + (size_t)K * RCAP);          // K
  int* res = cur + K;                                  // K

  const int t = threadIdx.x;
  const int e0 = blockIdx.x * CHUNK;
  const int e1 = min(e0 + CHUNK, E);

  for (int b = t; b < K; b += TPB) cur[b] = 0;
  __syncthreads();

  for (int base = e0 + 8 * t; base < e1; base += 8 * TPB) {
    if (base + 8 <= e1) {
      int4 dv0 = *reinterpret_cast<const int4*>(dst + base);
      int4 dv1 = *reinterpret_cast<const int4*>(dst + base + 4);
      int4 sv0 = *reinterpret_cast<const int4*>(src + base);
      int4 sv1 = *reinterpret_cast<const int4*>(src + base + 4);
      int d[8] = {dv0.x, dv0.y, dv0.z, dv0.w, dv1.x, dv1.y, dv1.z, dv1.w};
      int s[8] = {sv0.x, sv0.y, sv0.z, sv0.w, sv1.x, sv1.y, sv1.z, sv1.w};
#pragma unroll
      for (int j = 0; j < 8; ++j) {
        int b = d[j] >> LOG_NPB;
        unsigned pk = ((unsigned)s[j] << LOG_NPB) | (unsigned)(d[j] & (NPB - 1));
        int p = atomicAdd(&cur[b], 1);
        if (p < RCAP) {
          stage[b * RCAP + p] = pk;
        } else {                       // rare overflow: direct global slot
          int gp = atomicAdd(&gcur[b], 1);
          if (gp < capG) packed[(size_t)b * capG + gp] = pk;
        }
      }
    } else {
      for (int idx = base; idx < e1; ++idx) {
        int d = dst[idx], s = src[idx];
        int b = d >> LOG_NPB;
        unsigned pk = ((unsigned)s << LOG_NPB) | (unsigned)(d & (NPB - 1));
        int p = atomicAdd(&cur[b], 1);
        if (p < RCAP) {
          stage[b * RCAP + p] = pk;
        } else {
          int gp = atomicAdd(&gcur[b], 1);
          if (gp < capG) packed[(size_t)b * capG + gp] = pk;
        }
      }
    }
  }
  __syncthreads();

  if (t < K) {
    int c = min(cur[t], RCAP);
    res[t] = (c > 0) ? atomicAdd(&gcur[t], c) : 0;
  }
  __syncthreads();

  const int tot = K * RCAP;
  for (int i = t; i < tot; i += TPB) {
    int b = i / RCAP;
    int pos = i - b * RCAP;
    if (pos < min(cur[b], RCAP)) {
      int gp = res[b] + pos;
      if (gp < capG) packed[(size_t)b * capG + gp] = stage[i];
    }
  }
}

__device__ __forceinline__ void slice_range(int cnt, int s, int& off0, int& off1) {
  off0 = (int)(((long long)cnt * s) / SPLIT) & ~3;
  off1 = (s == SPLIT - 1) ? cnt : (int)(((long long)cnt * (s + 1)) / SPLIT) & ~3;
}

__global__ __launch_bounds__(TPB) void
k_deg(const unsigned int* __restrict__ packed, const int* __restrict__ gcur,
      int cap, int* __restrict__ pdeg, int Npad) {
  int b = blockIdx.x / SPLIT, s = blockIdx.x % SPLIT;
  __shared__ int bins[NPB];
  for (int i = threadIdx.x; i < NPB; i += TPB) bins[i] = 0;
  __syncthreads();
  int cnt = min(gcur[b], cap);
  int off0, off1; slice_range(cnt, s, off0, off1);
  const unsigned int* base = packed + (size_t)b * cap;
  int len = off1 - off0;
  int nfull = len >> 3;
  for (int g = threadIdx.x; g < nfull; g += TPB) {
    int e = off0 + (g << 3);
    uint4 pa = *reinterpret_cast<const uint4*>(base + e);
    uint4 pb = *reinterpret_cast<const uint4*>(base + e + 4);
    atomicAdd(&bins[pa.x & (NPB - 1)], 1);
    atomicAdd(&bins[pa.y & (NPB - 1)], 1);
    atomicAdd(&bins[pa.z & (NPB - 1)], 1);
    atomicAdd(&bins[pa.w & (NPB - 1)], 1);
    atomicAdd(&bins[pb.x & (NPB - 1)], 1);
    atomicAdd(&bins[pb.y & (NPB - 1)], 1);
    atomicAdd(&bins[pb.z & (NPB - 1)], 1);
    atomicAdd(&bins[pb.w & (NPB - 1)], 1);
  }
  for (int e = off0 + (nfull << 3) + threadIdx.x; e < off1; e += TPB)
    atomicAdd(&bins[base[e] & (NPB - 1)], 1);
  __syncthreads();
  int nb = b << LOG_NPB;
  for (int i = threadIdx.x; i < NPB; i += TPB)
    pdeg[s * Npad + nb + i] = bins[i];
}

__global__ void k_dinv(const int* __restrict__ pdeg, const float* __restrict__ x,
                       float* __restrict__ dinv, float* __restrict__ xd,
                       int N, int Npad) {
  int i = blockIdx.x * TPB + threadIdx.x;
  if (i >= N) return;
  int d = 1;  // self-loop
#pragma unroll
  for (int s = 0; s < SPLIT; ++s) d += pdeg[s * Npad + i];
  float di = rsqrtf((float)d);
  dinv[i] = di;
  xd[i] = x[i] * di;
}

__global__ __launch_bounds__(TPB) void
k_pass1(const unsigned int* __restrict__ packed, const int* __restrict__ gcur,
        int cap, const float* __restrict__ xd, float* __restrict__ pt1, int Npad) {
  int b = blockIdx.x / SPLIT, s = blockIdx.x % SPLIT;
  __shared__ float bins[NPB];
  for (int i = threadIdx.x; i < NPB; i += TPB) bins[i] = 0.f;
  __syncthreads();
  int cnt = min(gcur[b], cap);
  int off0, off1; slice_range(cnt, s, off0, off1);
  const unsigned int* base = packed + (size_t)b * cap;
  int len = off1 - off0;
  int nfull = len >> 3;
  for (int g = threadIdx.x; g < nfull; g += TPB) {
    int e = off0 + (g << 3);
    uint4 pa = *reinterpret_cast<const uint4*>(base + e);
    uint4 pb = *reinterpret_cast<const uint4*>(base + e + 4);
    float v0 = xd[pa.x >> LOG_NPB];
    float v1 = xd[pa.y >> LOG_NPB];
    float v2 = xd[pa.z >> LOG_NPB];
    float v3 = xd[pa.w >> LOG_NPB];
    float v4 = xd[pb.x >> LOG_NPB];
    float v5 = xd[pb.y >> LOG_NPB];
    float v6 = xd[pb.z >> LOG_NPB];
    float v7 = xd[pb.w >> LOG_NPB];
    atomicAdd(&bins[pa.x & (NPB - 1)], v0);
    atomicAdd(&bins[pa.y & (NPB - 1)], v1);
    atomicAdd(&bins[pa.z & (NPB - 1)], v2);
    atomicAdd(&bins[pa.w & (NPB - 1)], v3);
    atomicAdd(&bins[pb.x & (NPB - 1)], v4);
    atomicAdd(&bins[pb.y & (NPB - 1)], v5);
    atomicAdd(&bins[pb.z & (NPB - 1)], v6);
    atomicAdd(&bins[pb.w & (NPB - 1)], v7);
  }
  for (int e = off0 + (nfull << 3) + threadIdx.x; e < off1; e += TPB) {
    unsigned int p = base[e];
    atomicAdd(&bins[p & (NPB - 1)], xd[p >> LOG_NPB]);
  }
  __syncthreads();
  int nb = b << LOG_NPB;
  for (int i = threadIdx.x; i < NPB; i += TPB)
    pt1[s * Npad + nb + i] = bins[i];
}

__global__ void k_node(const float* __restrict__ pt1, const float* __restrict__ xd,
                       const float* __restrict__ dinv,
                       const float* __restrict__ W1, const float* __restrict__ b1,
                       const float* __restrict__ W2,
                       unsigned* __restrict__ gdp, int N, int Npad) {
  int i = blockIdx.x * TPB + threadIdx.x;
  if (i >= N) return;
  float tv = 0.f;
#pragma unroll
  for (int s = 0; s < SPLIT; ++s) tv += pt1[s * Npad + i];
  float di = dinv[i];
  float sv = di * (tv + xd[i]);
  float g0 = 0.f, g1 = 0.f;
#pragma unroll
  for (int j = 0; j < 16; ++j) {
    float h = fmaxf(fmaf(sv, W1[j], b1[j]), 0.f);
    g0 = fmaf(h, W2[2 * j], g0);
    g1 = fmaf(h, W2[2 * j + 1], g1);
  }
  __half2 h2 = __floats2half2_rn(g0 * di, g1 * di);
  gdp[i] = *reinterpret_cast<unsigned*>(&h2);
}

__global__ __launch_bounds__(TPB) void
k_pass2(const unsigned int* __restrict__ packed, const int* __restrict__ gcur,
        int cap, const unsigned* __restrict__ gdp, float* __restrict__ pt2, int Npad) {
  int b = blockIdx.x / SPLIT, s = blockIdx.x % SPLIT;
  __shared__ unsigned bins[NPB];          // packed f16x2 accumulators
  for (int i = threadIdx.x; i < NPB; i += TPB) bins[i] = 0u;  // (+0,+0)
  __syncthreads();
  int cnt = min(gcur[b], cap);
  int off0, off1; slice_range(cnt, s, off0, off1);
  const unsigned int* base = packed + (size_t)b * cap;
  int len = off1 - off0;
  int nfull = len >> 3;
  for (int g = threadIdx.x; g < nfull; g += TPB) {
    int e = off0 + (g << 3);
    uint4 pa = *reinterpret_cast<const uint4*>(base + e);
    uint4 pb = *reinterpret_cast<const uint4*>(base + e + 4);
    unsigned v0 = gdp[pa.x >> LOG_NPB];
    unsigned v1 = gdp[pa.y >> LOG_NPB];
    unsigned v2 = gdp[pa.z >> LOG_NPB];
    unsigned v3 = gdp[pa.w >> LOG_NPB];
    unsigned v4 = gdp[pb.x >> LOG_NPB];
    unsigned v5 = gdp[pb.y >> LOG_NPB];
    unsigned v6 = gdp[pb.z >> LOG_NPB];
    unsigned v7 = gdp[pb.w >> LOG_NPB];
    lds_pk_add_f16(&bins[pa.x & (NPB - 1)], v0);
    lds_pk_add_f16(&bins[pa.y & (NPB - 1)], v1);
    lds_pk_add_f16(&bins[pa.z & (NPB - 1)], v2);
    lds_pk_add_f16(&bins[pa.w & (NPB - 1)], v3);
    lds_pk_add_f16(&bins[pb.x & (NPB - 1)], v4);
    lds_pk_add_f16(&bins[pb.y & (NPB - 1)], v5);
    lds_pk_add_f16(&bins[pb.z & (NPB - 1)], v6);
    lds_pk_add_f16(&bins[pb.w & (NPB - 1)], v7);
  }
  for (int e = off0 + (nfull << 3) + threadIdx.x; e < off1; e += TPB) {
    unsigned int p = base[e];
    lds_pk_add_f16(&bins[p & (NPB - 1)], gdp[p >> LOG_NPB]);
  }
  __syncthreads();
  int nb = b << LOG_NPB;
  for (int i = threadIdx.x; i < NPB; i += TPB) {
    __half2 h = *reinterpret_cast<__half2*>(&bins[i]);
    float2 o;
    o.x = __low2float(h);
    o.y = __high2float(h);
    *reinterpret_cast<float2*>(pt2 + (size_t)s * 2 * Npad + 2 * (nb + i)) = o;
  }
}

__global__ void k_final(const float* __restrict__ pt2, const unsigned* __restrict__ gdp,
                        const float* __restrict__ dinv, const float* __restrict__ b2,
                        float* __restrict__ out, int N, int Npad) {
  int i = blockIdx.x * TPB + threadIdx.x;
  if (i >= N) return;
  float t0 = 0.f, t1 = 0.f;
#pragma unroll
  for (int s = 0; s < SPLIT; ++s) {
    float2 p = *reinterpret_cast<const float2*>(pt2 + (size_t)s * 2 * Npad + 2 * i);
    t0 += p.x;
    t1 += p.y;
  }
  unsigned gp = gdp[i];
  __half2 h = *reinterpret_cast<__half2*>(&gp);
  float di = dinv[i];
  float o0 = di * (t0 + __low2float(h)) + b2[0];
  float o1 = di * (t1 + __high2float(h)) + b2[1];
  float m = fmaxf(o0, o1);
  float l = m + logf(expf(o0 - m) + expf(o1 - m));
  out[2 * i] = o0 - l;
  out[2 * i + 1] = o1 - l;
}

extern "C" void kernel_launch(void* const* d_in, const int* in_sizes, int n_in,
                              void* d_out, int out_size, void* d_ws, size_t ws_size,
                              hipStream_t stream) {
  const float* x  = (const float*)d_in[0];
  const int*   ei = (const int*)d_in[1];
  const float* W1 = (const float*)d_in[2];
  const float* b1 = (const float*)d_in[3];
  const float* W2 = (const float*)d_in[4];
  const float* b2 = (const float*)d_in[5];

  const int N = in_sizes[0];      // x is [N,1]
  const int E = in_sizes[1] / 2;  // edge_index is [2,E]
  const int* src = ei;
  const int* dst = ei + E;

  const int K = (N + NPB - 1) >> LOG_NPB;   // 196
  const int Npad = K << LOG_NPB;            // 100352
  int mean = (int)(((long long)E * NPB) / N);
  int cap = mean + mean / 16 + 512;
  cap = (cap + 3) & ~3;

  char* ws = (char*)d_ws;
  auto align256 = [&](size_t n) { char* p = ws; ws += (n + 255) & ~(size_t)255; return p; };

  int*          gcur   = (int*)align256((size_t)K * 4);
  unsigned int* packed = (unsigned int*)align256((size_t)K * cap * 4);
  float*        dinv   = (float*)align256((size_t)N * 4);
  float*        xd     = (float*)align256((size_t)N * 4);
  unsigned*     gdp    = (unsigned*)align256((size_t)N * 4);
  // shared region R: pdeg / pt1 / pt2 (sequentially dead -> alias)
  float*        R      = (float*)align256((size_t)SPLIT * 2 * Npad * 4);
  int*          pdeg   = (int*)R;
  float*        pt1    = R;
  float*        pt2    = R;

  float* out = (float*)d_out;

  int nb_node   = (N + TPB - 1) / TPB;
  int nb_bucket = (E + CHUNK - 1) / CHUNK;
  int nb_acc    = K * SPLIT;
  size_t sh_bucket = ((size_t)K * RCAP + 2 * (size_t)K) * 4;

  k_reset <<<(K + TPB - 1) / TPB, TPB, 0, stream>>>(gcur, K);
  k_bucket<<<nb_bucket, TPB, sh_bucket, stream>>>(src, dst, E, K, cap, gcur, packed);
  k_deg   <<<nb_acc, TPB, 0, stream>>>(packed, gcur, cap, pdeg, Npad);
  k_dinv  <<<nb_node, TPB, 0, stream>>>(pdeg, x, dinv, xd, N, Npad);
  k_pass1 <<<nb_acc, TPB, 0, stream>>>(packed, gcur, cap, xd, pt1, Npad);
  k_node  <<<nb_node, TPB, 0, stream>>>(pt1, xd, dinv, W1, b1, W2, gdp, N, Npad);
  k_pass2 <<<nb_acc, TPB, 0, stream>>>(packed, gcur, cap, gdp, pt2, Npad);
  k_final <<<nb_node, TPB, 0, stream>>>(pt2, gdp, dinv, b2, out, N, Npad);
}

// Round 11
// 146.708 us; speedup vs baseline: 1.1879x; 1.1846x over previous
//
#include <hip/hip_runtime.h>
#include <hip/hip_fp16.h>

#define TPB 256
#define LOG_NPB 9
#define NPB 512            // nodes per bucket (bucket = dst >> 9)
#define SPLIT 16           // blocks per bucket in accumulation passes
#define CHUNK 4096         // edges per bucketing block
#define RCAP 40            // per-(chunk,bucket) LDS region cap (λ=21, +4σ; overflow handled)

// GCN collapse (in-dim=1, out-dim=2):
//   deg[n] = 1 + #incoming; dinv = deg^-1/2; xd = x*dinv
//   t1[n] = sum_{e:dst=n} xd[src];  s = dinv*(t1+xd)
//   g[n][k] = sum_j relu(s*W1[j]+b1[j])*W2[j][k];  gd = g*dinv (packed f16x2)
//   t2[n][k] = sum_{e:dst=n} gd[src][k]   (ONE ds_pk_add_f16 per edge)
//   o = dinv*(t2+gd) + b2;  out = log_softmax(o)
// Cost currency (R6 ablation): DS-pipe atomic instructions/edge at constant
// same-address collision rate (~3.2 cyc/lane-atomic, ~28-36us per pass).
// R9: pk-packing two NODES/word doubles collisions -> regression.
// R10: CHUNK 2048 doubles per-block fixed costs -> regression.
// This is the R8 best-known config + R9's verified bucket micro-win
// (8-edge ILP batch, RCAP 40).

__device__ __forceinline__ void lds_pk_add_f16(unsigned* addr, unsigned val) {
  asm volatile("ds_pk_add_f16 %0, %1"
               :: "v"((unsigned)(unsigned long long)addr), "v"(val)
               : "memory");
}

__global__ void k_reset(int* __restrict__ gcur, int K) {
  int i = blockIdx.x * blockDim.x + threadIdx.x;
  if (i < K) gcur[i] = 0;
}

// Single-atomic region-scatter bucketing (8-edge ILP batches).
__global__ __launch_bounds__(TPB) void
k_bucket(const int* __restrict__ src, const int* __restrict__ dst,
         int E, int K, int capG,
         int* __restrict__ gcur, unsigned int* __restrict__ packed) {
  extern __shared__ unsigned smem[];
  unsigned* stage = smem;                              // K*RCAP
  int* cur = (int*)(smem + (size_t)K * RCAP);          // K
  int* res = cur + K;                                  // K

  const int t = threadIdx.x;
  const int e0 = blockIdx.x * CHUNK;
  const int e1 = min(e0 + CHUNK, E);

  for (int b = t; b < K; b += TPB) cur[b] = 0;
  __syncthreads();

  for (int base = e0 + 8 * t; base < e1; base += 8 * TPB) {
    if (base + 8 <= e1) {
      int4 dv0 = *reinterpret_cast<const int4*>(dst + base);
      int4 dv1 = *reinterpret_cast<const int4*>(dst + base + 4);
      int4 sv0 = *reinterpret_cast<const int4*>(src + base);
      int4 sv1 = *reinterpret_cast<const int4*>(src + base + 4);
      int d[8] = {dv0.x, dv0.y, dv0.z, dv0.w, dv1.x, dv1.y, dv1.z, dv1.w};
      int s[8] = {sv0.x, sv0.y, sv0.z, sv0.w, sv1.x, sv1.y, sv1.z, sv1.w};
#pragma unroll
      for (int j = 0; j < 8; ++j) {
        int b = d[j] >> LOG_NPB;
        unsigned pk = ((unsigned)s[j] << LOG_NPB) | (unsigned)(d[j] & (NPB - 1));
        int p = atomicAdd(&cur[b], 1);
        if (p < RCAP) {
          stage[b * RCAP + p] = pk;
        } else {                       // rare overflow: direct global slot
          int gp = atomicAdd(&gcur[b], 1);
          if (gp < capG) packed[(size_t)b * capG + gp] = pk;
        }
      }
    } else {
      for (int idx = base; idx < e1; ++idx) {
        int d = dst[idx], s = src[idx];
        int b = d >> LOG_NPB;
        unsigned pk = ((unsigned)s << LOG_NPB) | (unsigned)(d & (NPB - 1));
        int p = atomicAdd(&cur[b], 1);
        if (p < RCAP) {
          stage[b * RCAP + p] = pk;
        } else {
          int gp = atomicAdd(&gcur[b], 1);
          if (gp < capG) packed[(size_t)b * capG + gp] = pk;
        }
      }
    }
  }
  __syncthreads();

  if (t < K) {
    int c = min(cur[t], RCAP);
    res[t] = (c > 0) ? atomicAdd(&gcur[t], c) : 0;
  }
  __syncthreads();

  const int tot = K * RCAP;
  for (int i = t; i < tot; i += TPB) {
    int b = i / RCAP;
    int pos = i - b * RCAP;
    if (pos < min(cur[b], RCAP)) {
      int gp = res[b] + pos;
      if (gp < capG) packed[(size_t)b * capG + gp] = stage[i];
    }
  }
}

__device__ __forceinline__ void slice_range(int cnt, int s, int& off0, int& off1) {
  off0 = (int)(((long long)cnt * s) / SPLIT) & ~3;
  off1 = (s == SPLIT - 1) ? cnt : (int)(((long long)cnt * (s + 1)) / SPLIT) & ~3;
}

__global__ __launch_bounds__(TPB) void
k_deg(const unsigned int* __restrict__ packed, const int* __restrict__ gcur,
      int cap, int* __restrict__ pdeg, int Npad) {
  int b = blockIdx.x / SPLIT, s = blockIdx.x % SPLIT;
  __shared__ int bins[NPB];
  for (int i = threadIdx.x; i < NPB; i += TPB) bins[i] = 0;
  __syncthreads();
  int cnt = min(gcur[b], cap);
  int off0, off1; slice_range(cnt, s, off0, off1);
  const unsigned int* base = packed + (size_t)b * cap;
  int len = off1 - off0;
  int nfull = len >> 3;
  for (int g = threadIdx.x; g < nfull; g += TPB) {
    int e = off0 + (g << 3);
    uint4 pa = *reinterpret_cast<const uint4*>(base + e);
    uint4 pb = *reinterpret_cast<const uint4*>(base + e + 4);
    atomicAdd(&bins[pa.x & (NPB - 1)], 1);
    atomicAdd(&bins[pa.y & (NPB - 1)], 1);
    atomicAdd(&bins[pa.z & (NPB - 1)], 1);
    atomicAdd(&bins[pa.w & (NPB - 1)], 1);
    atomicAdd(&bins[pb.x & (NPB - 1)], 1);
    atomicAdd(&bins[pb.y & (NPB - 1)], 1);
    atomicAdd(&bins[pb.z & (NPB - 1)], 1);
    atomicAdd(&bins[pb.w & (NPB - 1)], 1);
  }
  for (int e = off0 + (nfull << 3) + threadIdx.x; e < off1; e += TPB)
    atomicAdd(&bins[base[e] & (NPB - 1)], 1);
  __syncthreads();
  int nb = b << LOG_NPB;
  for (int i = threadIdx.x; i < NPB; i += TPB)
    pdeg[s * Npad + nb + i] = bins[i];
}

__global__ void k_dinv(const int* __restrict__ pdeg, const float* __restrict__ x,
                       float* __restrict__ dinv, float* __restrict__ xd,
                       int N, int Npad) {
  int i = blockIdx.x * TPB + threadIdx.x;
  if (i >= N) return;
  int d = 1;  // self-loop
#pragma unroll
  for (int s = 0; s < SPLIT; ++s) d += pdeg[s * Npad + i];
  float di = rsqrtf((float)d);
  dinv[i] = di;
  xd[i] = x[i] * di;
}

__global__ __launch_bounds__(TPB) void
k_pass1(const unsigned int* __restrict__ packed, const int* __restrict__ gcur,
        int cap, const float* __restrict__ xd, float* __restrict__ pt1, int Npad) {
  int b = blockIdx.x / SPLIT, s = blockIdx.x % SPLIT;
  __shared__ float bins[NPB];
  for (int i = threadIdx.x; i < NPB; i += TPB) bins[i] = 0.f;
  __syncthreads();
  int cnt = min(gcur[b], cap);
  int off0, off1; slice_range(cnt, s, off0, off1);
  const unsigned int* base = packed + (size_t)b * cap;
  int len = off1 - off0;
  int nfull = len >> 3;
  for (int g = threadIdx.x; g < nfull; g += TPB) {
    int e = off0 + (g << 3);
    uint4 pa = *reinterpret_cast<const uint4*>(base + e);
    uint4 pb = *reinterpret_cast<const uint4*>(base + e + 4);
    float v0 = xd[pa.x >> LOG_NPB];
    float v1 = xd[pa.y >> LOG_NPB];
    float v2 = xd[pa.z >> LOG_NPB];
    float v3 = xd[pa.w >> LOG_NPB];
    float v4 = xd[pb.x >> LOG_NPB];
    float v5 = xd[pb.y >> LOG_NPB];
    float v6 = xd[pb.z >> LOG_NPB];
    float v7 = xd[pb.w >> LOG_NPB];
    atomicAdd(&bins[pa.x & (NPB - 1)], v0);
    atomicAdd(&bins[pa.y & (NPB - 1)], v1);
    atomicAdd(&bins[pa.z & (NPB - 1)], v2);
    atomicAdd(&bins[pa.w & (NPB - 1)], v3);
    atomicAdd(&bins[pb.x & (NPB - 1)], v4);
    atomicAdd(&bins[pb.y & (NPB - 1)], v5);
    atomicAdd(&bins[pb.z & (NPB - 1)], v6);
    atomicAdd(&bins[pb.w & (NPB - 1)], v7);
  }
  for (int e = off0 + (nfull << 3) + threadIdx.x; e < off1; e += TPB) {
    unsigned int p = base[e];
    atomicAdd(&bins[p & (NPB - 1)], xd[p >> LOG_NPB]);
  }
  __syncthreads();
  int nb = b << LOG_NPB;
  for (int i = threadIdx.x; i < NPB; i += TPB)
    pt1[s * Npad + nb + i] = bins[i];
}

__global__ void k_node(const float* __restrict__ pt1, const float* __restrict__ xd,
                       const float* __restrict__ dinv,
                       const float* __restrict__ W1, const float* __restrict__ b1,
                       const float* __restrict__ W2,
                       unsigned* __restrict__ gdp, int N, int Npad) {
  int i = blockIdx.x * TPB + threadIdx.x;
  if (i >= N) return;
  float tv = 0.f;
#pragma unroll
  for (int s = 0; s < SPLIT; ++s) tv += pt1[s * Npad + i];
  float di = dinv[i];
  float sv = di * (tv + xd[i]);
  float g0 = 0.f, g1 = 0.f;
#pragma unroll
  for (int j = 0; j < 16; ++j) {
    float h = fmaxf(fmaf(sv, W1[j], b1[j]), 0.f);
    g0 = fmaf(h, W2[2 * j], g0);
    g1 = fmaf(h, W2[2 * j + 1], g1);
  }
  __half2 h2 = __floats2half2_rn(g0 * di, g1 * di);
  gdp[i] = *reinterpret_cast<unsigned*>(&h2);
}

__global__ __launch_bounds__(TPB) void
k_pass2(const unsigned int* __restrict__ packed, const int* __restrict__ gcur,
        int cap, const unsigned* __restrict__ gdp, float* __restrict__ pt2, int Npad) {
  int b = blockIdx.x / SPLIT, s = blockIdx.x % SPLIT;
  __shared__ unsigned bins[NPB];          // packed f16x2 accumulators
  for (int i = threadIdx.x; i < NPB; i += TPB) bins[i] = 0u;  // (+0,+0)
  __syncthreads();
  int cnt = min(gcur[b], cap);
  int off0, off1; slice_range(cnt, s, off0, off1);
  const unsigned int* base = packed + (size_t)b * cap;
  int len = off1 - off0;
  int nfull = len >> 3;
  for (int g = threadIdx.x; g < nfull; g += TPB) {
    int e = off0 + (g << 3);
    uint4 pa = *reinterpret_cast<const uint4*>(base + e);
    uint4 pb = *reinterpret_cast<const uint4*>(base + e + 4);
    unsigned v0 = gdp[pa.x >> LOG_NPB];
    unsigned v1 = gdp[pa.y >> LOG_NPB];
    unsigned v2 = gdp[pa.z >> LOG_NPB];
    unsigned v3 = gdp[pa.w >> LOG_NPB];
    unsigned v4 = gdp[pb.x >> LOG_NPB];
    unsigned v5 = gdp[pb.y >> LOG_NPB];
    unsigned v6 = gdp[pb.z >> LOG_NPB];
    unsigned v7 = gdp[pb.w >> LOG_NPB];
    lds_pk_add_f16(&bins[pa.x & (NPB - 1)], v0);
    lds_pk_add_f16(&bins[pa.y & (NPB - 1)], v1);
    lds_pk_add_f16(&bins[pa.z & (NPB - 1)], v2);
    lds_pk_add_f16(&bins[pa.w & (NPB - 1)], v3);
    lds_pk_add_f16(&bins[pb.x & (NPB - 1)], v4);
    lds_pk_add_f16(&bins[pb.y & (NPB - 1)], v5);
    lds_pk_add_f16(&bins[pb.z & (NPB - 1)], v6);
    lds_pk_add_f16(&bins[pb.w & (NPB - 1)], v7);
  }
  for (int e = off0 + (nfull << 3) + threadIdx.x; e < off1; e += TPB) {
    unsigned int p = base[e];
    lds_pk_add_f16(&bins[p & (NPB - 1)], gdp[p >> LOG_NPB]);
  }
  __syncthreads();
  int nb = b << LOG_NPB;
  for (int i = threadIdx.x; i < NPB; i += TPB) {
    __half2 h = *reinterpret_cast<__half2*>(&bins[i]);
    float2 o;
    o.x = __low2float(h);
    o.y = __high2float(h);
    *reinterpret_cast<float2*>(pt2 + (size_t)s * 2 * Npad + 2 * (nb + i)) = o;
  }
}

__global__ void k_final(const float* __restrict__ pt2, const unsigned* __restrict__ gdp,
                        const float* __restrict__ dinv, const float* __restrict__ b2,
                        float* __restrict__ out, int N, int Npad) {
  int i = blockIdx.x * TPB + threadIdx.x;
  if (i >= N) return;
  float t0 = 0.f, t1 = 0.f;
#pragma unroll
  for (int s = 0; s < SPLIT; ++s) {
    float2 p = *reinterpret_cast<const float2*>(pt2 + (size_t)s * 2 * Npad + 2 * i);
    t0 += p.x;
    t1 += p.y;
  }
  unsigned gp = gdp[i];
  __half2 h = *reinterpret_cast<__half2*>(&gp);
  float di = dinv[i];
  float o0 = di * (t0 + __low2float(h)) + b2[0];
  float o1 = di * (t1 + __high2float(h)) + b2[1];
  float m = fmaxf(o0, o1);
  float l = m + logf(expf(o0 - m) + expf(o1 - m));
  out[2 * i] = o0 - l;
  out[2 * i + 1] = o1 - l;
}

extern "C" void kernel_launch(void* const* d_in, const int* in_sizes, int n_in,
                              void* d_out, int out_size, void* d_ws, size_t ws_size,
                              hipStream_t stream) {
  const float* x  = (const float*)d_in[0];
  const int*   ei = (const int*)d_in[1];
  const float* W1 = (const float*)d_in[2];
  const float* b1 = (const float*)d_in[3];
  const float* W2 = (const float*)d_in[4];
  const float* b2 = (const float*)d_in[5];

  const int N = in_sizes[0];      // x is [N,1]
  const int E = in_sizes[1] / 2;  // edge_index is [2,E]
  const int* src = ei;
  const int* dst = ei + E;

  const int K = (N + NPB - 1) >> LOG_NPB;   // 196
  const int Npad = K << LOG_NPB;            // 100352
  int mean = (int)(((long long)E * NPB) / N);
  int cap = mean + mean / 16 + 512;
  cap = (cap + 3) & ~3;

  char* ws = (char*)d_ws;
  auto align256 = [&](size_t n) { char* p = ws; ws += (n + 255) & ~(size_t)255; return p; };

  int*          gcur   = (int*)align256((size_t)K * 4);
  unsigned int* packed = (unsigned int*)align256((size_t)K * cap * 4);
  float*        dinv   = (float*)align256((size_t)N * 4);
  float*        xd     = (float*)align256((size_t)N * 4);
  unsigned*     gdp    = (unsigned*)align256((size_t)N * 4);
  // shared region R: pdeg / pt1 / pt2 (sequentially dead -> alias)
  float*        R      = (float*)align256((size_t)SPLIT * 2 * Npad * 4);
  int*          pdeg   = (int*)R;
  float*        pt1    = R;
  float*        pt2    = R;

  float* out = (float*)d_out;

  int nb_node   = (N + TPB - 1) / TPB;
  int nb_bucket = (E + CHUNK - 1) / CHUNK;
  int nb_acc    = K * SPLIT;
  size_t sh_bucket = ((size_t)K * RCAP + 2 * (size_t)K) * 4;

  k_reset <<<(K + TPB - 1) / TPB, TPB, 0, stream>>>(gcur, K);
  k_bucket<<<nb_bucket, TPB, sh_bucket, stream>>>(src, dst, E, K, cap, gcur, packed);
  k_deg   <<<nb_acc, TPB, 0, stream>>>(packed, gcur, cap, pdeg, Npad);
  k_dinv  <<<nb_node, TPB, 0, stream>>>(pdeg, x, dinv, xd, N, Npad);
  k_pass1 <<<nb_acc, TPB, 0, stream>>>(packed, gcur, cap, xd, pt1, Npad);
  k_node  <<<nb_node, TPB, 0, stream>>>(pt1, xd, dinv, W1, b1, W2, gdp, N, Npad);
  k_pass2 <<<nb_acc, TPB, 0, stream>>>(packed, gcur, cap, gdp, pt2, Npad);
  k_final <<<nb_node, TPB, 0, stream>>>(pt2, gdp, dinv, b2, out, N, Npad);
}